// Round 4
// baseline (140.977 us; speedup 1.0000x reference)
//
#include <hip/hip_runtime.h>

#define IN_C 64
#define OUT_C 16
#define EA_D 8

typedef float f32x4 __attribute__((ext_vector_type(4)));
typedef float f32x2 __attribute__((ext_vector_type(2)));

// DPP cross-lane move, VALU-speed (no DS latency, no lgkmcnt):
//   0x140 row_mirror        (i -> 15-i within each 16-lane row)
//   0x141 row_half_mirror   (i -> (i&8) | (7-(i&7)))
//   0x4E  quad_perm [2,3,0,1]  (xor 2)
//   0xB1  quad_perm [1,0,3,2]  (xor 1)
// These four involutions form a complete butterfly over each aligned
// 16-lane group.
#define DPPF(x, ctrl) \
    __uint_as_float((unsigned)__builtin_amdgcn_update_dpp( \
        0, (int)__float_as_uint(x), (ctrl), 0xF, 0xF, true))

__device__ __forceinline__ void atomic_add_f32(float* p, float v) {
#if defined(__HIP_PLATFORM_AMD__) || defined(__AMDGCN__)
    unsafeAtomicAdd(p, v);   // global_atomic_add_f32, no CAS loop
#else
    atomicAdd(p, v);
#endif
}

// ---------------- h = x @ lin_w + lin_b  (also zeroes out[]) ----------------
// 2 nodes x 2 channels per thread, 256-thread blocks, 64-node tiles.
// Design point chosen from the r0/r3 measurements:
//   r0 (1x1):  DS 800k wave-insts (~15.6us issue), 32 waves/CU  -> best so far
//   r3 (4x4):  DS 200k (~3.9us), but 8 waves/CU + 3 blocks/CU grid -> +11us
//   here(2x2): DS 400k (~7.8us, near the 6.1us HBM floor), 28 waves/CU
//              (21.8KB LDS -> 7 blocks/CU), grid 1563 (~6/CU, co-resident).
// Conflicts: xv = 8 distinct rows/wave, bank-starts 4*ng mod 32 all distinct
// -> free; wv = 8 rows at {0,8,16,24}x2 -> 2-way = free (m136). b128 all
// 16B-aligned (row stride 68 floats). Weights stay in LDS (round-1 lesson:
// s_loads in the loop force lgkmcnt(0) drains that stall the DS pipe).
// Accumulation order (bias, then k ascending) identical -> h bit-exact.
__global__ __launch_bounds__(256) void h_kernel(
    const float* __restrict__ x,
    const float* __restrict__ lin_w,   // [64,16]
    const float* __restrict__ lin_b,   // [16]
    float* __restrict__ h,             // [N,16]
    float* __restrict__ out,           // [N,16] zero-init
    int n)
{
    __shared__ float s_x [64][IN_C + 4];   // 17.4 KB, stride 68 floats
    __shared__ float s_wt[16][IN_C + 4];   //  4.4 KB, transposed W: s_wt[c][k]

    const int t = threadIdx.x;
    const int nodeBase = blockIdx.x * 64;

    // zero out[]: 64 nodes * 16 ch = 1024 floats = one float4 per thread,
    // coalesced. (lim is a multiple of 16, idx a multiple of 4, so the
    // guard covers the whole float4.)
    {
        const int idx = nodeBase * OUT_C + t * 4;
        if (idx < n * OUT_C) *(f32x4*)(out + idx) = (f32x4){0.f, 0.f, 0.f, 0.f};
    }

    // stage transposed weights (one-time, 4 scalars per thread)
    #pragma unroll
    for (int i = t; i < IN_C * OUT_C; i += 256)
        s_wt[i & 15][i >> 4] = lin_w[i];

    // stage x tile: 64 rows x 16 float4 = 1024 float4s, 4 per thread,
    // coalesced (16 consecutive threads cover one 256B row).
    #pragma unroll
    for (int r = 0; r < 4; ++r) {
        const int i  = r * 256 + t;
        const int nd = i >> 4;
        const int k4 = (i & 15) * 4;
        const int node = nodeBase + nd;
        f32x4 v = {0.f, 0.f, 0.f, 0.f};
        if (node < n) v = *(const f32x4*)(x + (size_t)node * IN_C + k4);
        *(f32x4*)(&s_x[nd][k4]) = v;
    }
    __syncthreads();

    const int ng = t >> 3;          // 0..31: node slot (pair partner +32)
    const int c0 = (t & 7) * 2;     // channel pair: 0,2,...,14

    // named accumulators, all statically indexed (rule #20)
    float a00 = lin_b[c0], a01 = lin_b[c0 + 1];   // node ng
    float a10 = lin_b[c0], a11 = lin_b[c0 + 1];   // node ng+32

    #pragma unroll
    for (int k4 = 0; k4 < IN_C; k4 += 4) {
        const f32x4 w0 = *(const f32x4*)(&s_wt[c0    ][k4]);
        const f32x4 w1 = *(const f32x4*)(&s_wt[c0 + 1][k4]);
        const f32x4 x0 = *(const f32x4*)(&s_x[ng     ][k4]);
        const f32x4 x1 = *(const f32x4*)(&s_x[ng + 32][k4]);

        a00 = fmaf(x0.x, w0.x, a00); a00 = fmaf(x0.y, w0.y, a00);
        a00 = fmaf(x0.z, w0.z, a00); a00 = fmaf(x0.w, w0.w, a00);
        a01 = fmaf(x0.x, w1.x, a01); a01 = fmaf(x0.y, w1.y, a01);
        a01 = fmaf(x0.z, w1.z, a01); a01 = fmaf(x0.w, w1.w, a01);
        a10 = fmaf(x1.x, w0.x, a10); a10 = fmaf(x1.y, w0.y, a10);
        a10 = fmaf(x1.z, w0.z, a10); a10 = fmaf(x1.w, w0.w, a10);
        a11 = fmaf(x1.x, w1.x, a11); a11 = fmaf(x1.y, w1.y, a11);
        a11 = fmaf(x1.z, w1.z, a11); a11 = fmaf(x1.w, w1.w, a11);
    }

    // stores: 8 consecutive lanes cover one 64B h row; a wave's store inst
    // spans 512B contiguous.
    {
        const int node0 = nodeBase + ng;
        if (node0 < n) {
            f32x2 r = {a00, a01};
            *(f32x2*)(h + (size_t)node0 * OUT_C + c0) = r;
        }
        const int node1 = nodeBase + ng + 32;
        if (node1 < n) {
            f32x2 r = {a10, a11};
            *(f32x2*)(h + (size_t)node1 * OUT_C + c0) = r;
        }
    }
}

// ---------------- per-edge fused kernel: quad-per-edge ----------------
// ROUND-2 VERSION, unchanged (measured -2us vs the 131us baseline; it is
// latency/atomic-bound -- instruction trimming beyond this was ~neutral).
__global__ __launch_bounds__(256) void edge_kernel(
    const int*   __restrict__ edge_index,  // [2,E]
    const float* __restrict__ edge_attr,   // [E,8]
    const float* __restrict__ ea_w,        // [8,16]
    const float* __restrict__ ea_b,        // [16]
    const float* __restrict__ w1,          // [16]
    const float* __restrict__ b1,          // [16]
    const float* __restrict__ w2,          // [16]
    const float* __restrict__ b2,          // [1]
    const float* __restrict__ h,           // [N,16]
    float*       __restrict__ out,         // [N,16]
    int E)
{
    __shared__ float s_eawT[16][12];   // row c = ea_w[:,c]
    __shared__ float s_eab[OUT_C];

    const int t = threadIdx.x;
    if (t < 128)                s_eawT[t & 15][t >> 4] = ea_w[(t >> 4) * OUT_C + (t & 15)];
    else if (t < 128 + OUT_C)   s_eab[t - 128] = ea_b[t - 128];
    __syncthreads();

    const int gid = blockIdx.x * 256 + t;
    const int e = gid >> 4;
    const int c = gid & 15;
    if (e >= E) return;

    const int row = edge_index[e] - 1;     // edge_index[0][e] - 1
    const int col = edge_index[E + e];     // edge_index[1][e]

    // 32B broadcast per quad (contiguous across the 4 quads of a wave)
    const f32x4* ap = (const f32x4*)(edge_attr + (size_t)e * EA_D);
    const f32x4 a0 = ap[0], a1 = ap[1];

    // gather: 16 consecutive lanes read one 64B line of h
    const float hv = h[(size_t)col * OUT_C + c];

    // agg = h[col][c] * (edge_attr @ ea_w + ea_b)[c]; k ascending (bit-exact
    // vs baseline accumulation order).
    const f32x4 w0 = *(const f32x4*)(&s_eawT[c][0]);
    const f32x4 w4 = *(const f32x4*)(&s_eawT[c][4]);
    float d = s_eab[c];
    d = fmaf(a0.x, w0.x, d);
    d = fmaf(a0.y, w0.y, d);
    d = fmaf(a0.z, w0.z, d);
    d = fmaf(a0.w, w0.w, d);
    d = fmaf(a1.x, w4.x, d);
    d = fmaf(a1.y, w4.y, d);
    d = fmaf(a1.z, w4.z, d);
    d = fmaf(a1.w, w4.w, d);
    const float agg = hv * d;

    // score = b2 + sum_j relu(agg*w1[j]+b1[j])*w2[j]  (uniform scalar loads,
    // hoisted -- no DS interleave, so no lgkm trap here)
    float s = b2[0];
    #pragma unroll
    for (int j = 0; j < OUT_C; ++j) {
        const float hm = fmaf(agg, w1[j], b1[j]);
        s = fmaf(fmaxf(hm, 0.0f), w2[j], s);
    }

    // softmax over the 16 channels of this quad: DPP butterfly (max then sum)
    float m = s;
    m = fmaxf(m, DPPF(m, 0x140));
    m = fmaxf(m, DPPF(m, 0x141));
    m = fmaxf(m, DPPF(m, 0x4E));
    m = fmaxf(m, DPPF(m, 0xB1));

    const float p = __expf(s - m);
    float den = p;
    den += DPPF(den, 0x140);
    den += DPPF(den, 0x141);
    den += DPPF(den, 0x4E);
    den += DPPF(den, 0xB1);

    const float attn = p * __builtin_amdgcn_rcpf(den);

    // grouped scatter: one 64B line per quad
    atomic_add_f32(out + (size_t)row * OUT_C + c, agg * attn);
}

extern "C" void kernel_launch(void* const* d_in, const int* in_sizes, int n_in,
                              void* d_out, int out_size, void* d_ws, size_t ws_size,
                              hipStream_t stream)
{
    const float* x          = (const float*)d_in[0];
    const int*   edge_index = (const int*)  d_in[1];
    const float* edge_attr  = (const float*)d_in[2];
    const float* lin_w      = (const float*)d_in[3];
    const float* lin_b      = (const float*)d_in[4];
    const float* ea_w       = (const float*)d_in[5];
    const float* ea_b       = (const float*)d_in[6];
    const float* attn_w1    = (const float*)d_in[7];
    const float* attn_b1    = (const float*)d_in[8];
    const float* attn_w2    = (const float*)d_in[9];
    const float* attn_b2    = (const float*)d_in[10];

    const int n = in_sizes[0] / IN_C;      // 100000
    const int E = in_sizes[1] / 2;         // 400000

    float* h   = (float*)d_ws;             // [N,16] = 6.4 MB
    float* out = (float*)d_out;

    // h_kernel zeroes out[] (grid covers every out element exactly once)
    h_kernel<<<(n + 63) / 64, 256, 0, stream>>>(x, lin_w, lin_b, h, out, n);

    // 16 lanes per edge
    const long long threads = (long long)E * OUT_C;
    edge_kernel<<<(int)((threads + 255) / 256), 256, 0, stream>>>(
        edge_index, edge_attr, ea_w, ea_b,
        attn_w1, attn_b1, attn_w2, attn_b2,
        h, out, E);
}

// Round 5
// 129.403 us; speedup vs baseline: 1.0894x; 1.0894x over previous
//
#include <hip/hip_runtime.h>

#define IN_C 64
#define OUT_C 16
#define EA_D 8

typedef float f32x4 __attribute__((ext_vector_type(4)));
typedef float f32x2 __attribute__((ext_vector_type(2)));

// DPP cross-lane move, VALU-speed (no DS latency, no lgkmcnt):
//   0x140 row_mirror        (i -> 15-i within each 16-lane row)
//   0x141 row_half_mirror   (i -> (i&8) | (7-(i&7)))
//   0x4E  quad_perm [2,3,0,1]  (xor 2)
//   0xB1  quad_perm [1,0,3,2]  (xor 1)
#define DPPF(x, ctrl) \
    __uint_as_float((unsigned)__builtin_amdgcn_update_dpp( \
        0, (int)__float_as_uint(x), (ctrl), 0xF, 0xF, true))

__device__ __forceinline__ void atomic_add_f32(float* p, float v) {
#if defined(__HIP_PLATFORM_AMD__) || defined(__AMDGCN__)
    unsafeAtomicAdd(p, v);   // global_atomic_add_f32, no CAS loop
#else
    atomicAdd(p, v);
#endif
}

// ---------------- h = x @ lin_w + lin_b  (also zeroes out[]) ----------------
// 2 nodes x 2 channels per thread (DS/output 32 -> 16), with the round-3/4
// failure mode closed off: those two variants regressed IDENTICALLY (+11,+12)
// at wildly different LDS occupancy -> the common cause is the fully-unrolled
// multi-operand k-loop letting the compiler software-pipeline ~16 steps of
// b128 destinations into 200+ VGPRs (occupancy -> 2 waves/SIMD, m69).
// Valves here: #pragma unroll 2 (<=8 in-flight b128 quads) and
// __launch_bounds__(256, 8) (allocator capped at 64 VGPR = 8 waves/EU).
// Conflict design (unchanged from r4, verified): xv = 8 distinct rows/wave,
// bank-starts 4*ng mod 32 tile all 32 banks once -> free; wv = c0 and c0+8
// alias 2-way -> free (m136). Row stride 68 floats keeps b128 16B-aligned.
// Weights stay in LDS (r1 lesson: in-loop s_loads force lgkmcnt(0) drains).
// Accumulation order (bias, then k ascending, .x->.w) identical to the
// 128.97us baseline -> h bit-exact.
__global__ __launch_bounds__(256, 8) void h_kernel(
    const float* __restrict__ x,
    const float* __restrict__ lin_w,   // [64,16]
    const float* __restrict__ lin_b,   // [16]
    float* __restrict__ h,             // [N,16]
    float* __restrict__ out,           // [N,16] zero-init
    int n)
{
    __shared__ float s_x [64][IN_C + 4];   // 17.4 KB, stride 68 floats
    __shared__ float s_wt[16][IN_C + 4];   //  4.4 KB, transposed W: s_wt[c][k]

    const int t = threadIdx.x;
    const int nodeBase = blockIdx.x * 64;

    // zero out[]: 64 nodes * 16 ch = 1024 floats = one float4 per thread,
    // coalesced. (idx is a multiple of 4, lim a multiple of 16 -> the guard
    // covers the whole float4.)
    {
        const int idx = nodeBase * OUT_C + t * 4;
        if (idx < n * OUT_C) *(f32x4*)(out + idx) = (f32x4){0.f, 0.f, 0.f, 0.f};
    }

    // stage transposed weights (one-time, 4 scalars per thread)
    for (int i = t; i < IN_C * OUT_C; i += 256)
        s_wt[i & 15][i >> 4] = lin_w[i];

    // stage x tile: 64 rows x 16 float4, 4 per thread, coalesced
    // (16 consecutive threads cover one 256B row).
    #pragma unroll
    for (int r = 0; r < 4; ++r) {
        const int i  = r * 256 + t;
        const int nd = i >> 4;
        const int k4 = (i & 15) * 4;
        const int node = nodeBase + nd;
        f32x4 v = {0.f, 0.f, 0.f, 0.f};
        if (node < n) v = *(const f32x4*)(x + (size_t)node * IN_C + k4);
        *(f32x4*)(&s_x[nd][k4]) = v;
    }
    __syncthreads();

    const int ng = t >> 3;          // 0..31: node slot (pair partner +32)
    const int c0 = (t & 7) * 2;     // channel pair: 0,2,...,14

    // named accumulators, statically indexed (rule #20)
    float a00 = lin_b[c0], a01 = lin_b[c0 + 1];   // node ng
    float a10 = lin_b[c0], a11 = lin_b[c0 + 1];   // node ng+32

    // unroll 2, NOT full: limits the scheduler to ~8 in-flight b128
    // destinations so VGPR stays ~40 (the r3/r4 regression valve).
    #pragma unroll 2
    for (int k4 = 0; k4 < IN_C; k4 += 4) {
        const f32x4 w0 = *(const f32x4*)(&s_wt[c0    ][k4]);
        const f32x4 w1 = *(const f32x4*)(&s_wt[c0 + 1][k4]);
        const f32x4 x0 = *(const f32x4*)(&s_x[ng     ][k4]);
        const f32x4 x1 = *(const f32x4*)(&s_x[ng + 32][k4]);

        a00 = fmaf(x0.x, w0.x, a00); a00 = fmaf(x0.y, w0.y, a00);
        a00 = fmaf(x0.z, w0.z, a00); a00 = fmaf(x0.w, w0.w, a00);
        a01 = fmaf(x0.x, w1.x, a01); a01 = fmaf(x0.y, w1.y, a01);
        a01 = fmaf(x0.z, w1.z, a01); a01 = fmaf(x0.w, w1.w, a01);
        a10 = fmaf(x1.x, w0.x, a10); a10 = fmaf(x1.y, w0.y, a10);
        a10 = fmaf(x1.z, w0.z, a10); a10 = fmaf(x1.w, w0.w, a10);
        a11 = fmaf(x1.x, w1.x, a11); a11 = fmaf(x1.y, w1.y, a11);
        a11 = fmaf(x1.z, w1.z, a11); a11 = fmaf(x1.w, w1.w, a11);
    }

    // stores: 8 consecutive lanes cover one 64B h row; a wave writes two
    // 512B contiguous spans.
    {
        const int node0 = nodeBase + ng;
        if (node0 < n) {
            f32x2 r = {a00, a01};
            *(f32x2*)(h + (size_t)node0 * OUT_C + c0) = r;
        }
        const int node1 = nodeBase + ng + 32;
        if (node1 < n) {
            f32x2 r = {a10, a11};
            *(f32x2*)(h + (size_t)node1 * OUT_C + c0) = r;
        }
    }
}

// ---------------- per-edge fused kernel: quad-per-edge ----------------
// ROUND-2 VERSION, unchanged (measured winner; latency/atomic-bound).
__global__ __launch_bounds__(256) void edge_kernel(
    const int*   __restrict__ edge_index,  // [2,E]
    const float* __restrict__ edge_attr,   // [E,8]
    const float* __restrict__ ea_w,        // [8,16]
    const float* __restrict__ ea_b,        // [16]
    const float* __restrict__ w1,          // [16]
    const float* __restrict__ b1,          // [16]
    const float* __restrict__ w2,          // [16]
    const float* __restrict__ b2,          // [1]
    const float* __restrict__ h,           // [N,16]
    float*       __restrict__ out,         // [N,16]
    int E)
{
    __shared__ float s_eawT[16][12];   // row c = ea_w[:,c]
    __shared__ float s_eab[OUT_C];

    const int t = threadIdx.x;
    if (t < 128)                s_eawT[t & 15][t >> 4] = ea_w[(t >> 4) * OUT_C + (t & 15)];
    else if (t < 128 + OUT_C)   s_eab[t - 128] = ea_b[t - 128];
    __syncthreads();

    const int gid = blockIdx.x * 256 + t;
    const int e = gid >> 4;
    const int c = gid & 15;
    if (e >= E) return;

    const int row = edge_index[e] - 1;     // edge_index[0][e] - 1
    const int col = edge_index[E + e];     // edge_index[1][e]

    // 32B broadcast per quad (contiguous across the 4 quads of a wave)
    const f32x4* ap = (const f32x4*)(edge_attr + (size_t)e * EA_D);
    const f32x4 a0 = ap[0], a1 = ap[1];

    // gather: 16 consecutive lanes read one 64B line of h
    const float hv = h[(size_t)col * OUT_C + c];

    // agg = h[col][c] * (edge_attr @ ea_w + ea_b)[c]; k ascending (bit-exact
    // vs baseline accumulation order).
    const f32x4 w0 = *(const f32x4*)(&s_eawT[c][0]);
    const f32x4 w4 = *(const f32x4*)(&s_eawT[c][4]);
    float d = s_eab[c];
    d = fmaf(a0.x, w0.x, d);
    d = fmaf(a0.y, w0.y, d);
    d = fmaf(a0.z, w0.z, d);
    d = fmaf(a0.w, w0.w, d);
    d = fmaf(a1.x, w4.x, d);
    d = fmaf(a1.y, w4.y, d);
    d = fmaf(a1.z, w4.z, d);
    d = fmaf(a1.w, w4.w, d);
    const float agg = hv * d;

    // score = b2 + sum_j relu(agg*w1[j]+b1[j])*w2[j]  (uniform scalar loads)
    float s = b2[0];
    #pragma unroll
    for (int j = 0; j < OUT_C; ++j) {
        const float hm = fmaf(agg, w1[j], b1[j]);
        s = fmaf(fmaxf(hm, 0.0f), w2[j], s);
    }

    // softmax over the 16 channels of this quad: DPP butterfly (max then sum)
    float m = s;
    m = fmaxf(m, DPPF(m, 0x140));
    m = fmaxf(m, DPPF(m, 0x141));
    m = fmaxf(m, DPPF(m, 0x4E));
    m = fmaxf(m, DPPF(m, 0xB1));

    const float p = __expf(s - m);
    float den = p;
    den += DPPF(den, 0x140);
    den += DPPF(den, 0x141);
    den += DPPF(den, 0x4E);
    den += DPPF(den, 0xB1);

    const float attn = p * __builtin_amdgcn_rcpf(den);

    // grouped scatter: one 64B line per quad
    atomic_add_f32(out + (size_t)row * OUT_C + c, agg * attn);
}

extern "C" void kernel_launch(void* const* d_in, const int* in_sizes, int n_in,
                              void* d_out, int out_size, void* d_ws, size_t ws_size,
                              hipStream_t stream)
{
    const float* x          = (const float*)d_in[0];
    const int*   edge_index = (const int*)  d_in[1];
    const float* edge_attr  = (const float*)d_in[2];
    const float* lin_w      = (const float*)d_in[3];
    const float* lin_b      = (const float*)d_in[4];
    const float* ea_w       = (const float*)d_in[5];
    const float* ea_b       = (const float*)d_in[6];
    const float* attn_w1    = (const float*)d_in[7];
    const float* attn_b1    = (const float*)d_in[8];
    const float* attn_w2    = (const float*)d_in[9];
    const float* attn_b2    = (const float*)d_in[10];

    const int n = in_sizes[0] / IN_C;      // 100000
    const int E = in_sizes[1] / 2;         // 400000

    float* h   = (float*)d_ws;             // [N,16] = 6.4 MB
    float* out = (float*)d_out;

    // h_kernel zeroes out[] (grid covers every out element exactly once)
    h_kernel<<<(n + 63) / 64, 256, 0, stream>>>(x, lin_w, lin_b, h, out, n);

    // 16 lanes per edge
    const long long threads = (long long)E * OUT_C;
    edge_kernel<<<(int)((threads + 255) / 256), 256, 0, stream>>>(
        edge_index, edge_attr, ea_w, ea_b,
        attn_w1, attn_b1, attn_w2, attn_b2,
        h, out, E);
}